// Round 1
// baseline (1143.683 us; speedup 1.0000x reference)
//
#include <hip/hip_runtime.h>
#include <hip/hip_bf16.h>
#include <stdint.h>

#define NTOK 8192
#define DM   1024
#define DFF  4096
#define NE   8

typedef __bf16 bf16x8 __attribute__((ext_vector_type(8)));
typedef short  short8 __attribute__((ext_vector_type(8)));
typedef float  floatx4 __attribute__((ext_vector_type(4)));

// ---- workspace layout (bytes) ----
#define WS_CNT   0                           // 8 ints
#define WS_CUR   32                          // 8 ints
#define WS_OFF   64                          // 8 ints
#define WS_EIDX  1024                        // NTOK ints
#define WS_PERM  (WS_EIDX + NTOK * 4)        // NTOK ints
#define WS_XPERM (WS_PERM + NTOK * 4)        // (NTOK+128) x DM bf16
#define WS_HPERM (WS_XPERM + (NTOK + 128) * DM * 2)  // (NTOK+128) x DFF bf16
// total ~85.3 MB

__device__ __forceinline__ unsigned short f2bf(float f) {
  union { float f; unsigned u; } v; v.f = f;
  return (unsigned short)((v.u + 0x7FFFu + ((v.u >> 16) & 1u)) >> 16);
}

__device__ __forceinline__ float f4get(const float4& v, int i) {
  return i == 0 ? v.x : i == 1 ? v.y : i == 2 ? v.z : v.w;
}

__global__ void zero_ctrl_kernel(int* ctrl) {
  if (threadIdx.x < 16) ctrl[threadIdx.x] = 0;   // counts + cursors
}

// one wave per token: fp32 logits, argmax (first max), one-hot out, counts
__global__ __launch_bounds__(256) void gate_kernel(
    const float* __restrict__ x, const float* __restrict__ gW,
    const float* __restrict__ gb, float* __restrict__ gate_out,
    int* __restrict__ counts, int* __restrict__ eidx) {
  int wave = threadIdx.x >> 6;
  int lane = threadIdx.x & 63;
  int t = blockIdx.x * 4 + wave;
  const float4* xr = (const float4*)(x + (size_t)t * DM + lane * 16);
  float acc[8] = {0, 0, 0, 0, 0, 0, 0, 0};
#pragma unroll
  for (int q = 0; q < 4; ++q) {
    float4 xv = xr[q];
    int kbase = lane * 16 + q * 4;
#pragma unroll
    for (int d = 0; d < 4; ++d) {
      float xs = f4get(xv, d);
      const float4* g4 = (const float4*)(gW + (size_t)(kbase + d) * NE);
      float4 g0 = g4[0], g1 = g4[1];
      acc[0] += xs * g0.x; acc[1] += xs * g0.y;
      acc[2] += xs * g0.z; acc[3] += xs * g0.w;
      acc[4] += xs * g1.x; acc[5] += xs * g1.y;
      acc[6] += xs * g1.z; acc[7] += xs * g1.w;
    }
  }
#pragma unroll
  for (int off = 32; off > 0; off >>= 1) {
#pragma unroll
    for (int e = 0; e < 8; ++e) acc[e] += __shfl_down(acc[e], off);
  }
  if (lane == 0) {
    float best = acc[0] + gb[0];
    int bi = 0;
#pragma unroll
    for (int e = 1; e < 8; ++e) {
      float v = acc[e] + gb[e];
      if (v > best) { best = v; bi = e; }
    }
#pragma unroll
    for (int e = 0; e < 8; ++e) gate_out[(size_t)t * NE + e] = (e == bi) ? 1.0f : 0.0f;
    eidx[t] = bi;
    atomicAdd(&counts[bi], 1);
  }
}

__global__ void offsets_kernel(const int* __restrict__ counts, int* __restrict__ offs) {
  if (threadIdx.x == 0) {
    int s = 0;
    for (int e = 0; e < NE; ++e) { offs[e] = s; s += counts[e]; }
  }
}

// one wave per token: bucket + fp32->bf16 convert into permuted x
__global__ __launch_bounds__(256) void scatter_kernel(
    const float* __restrict__ x, const int* __restrict__ eidx,
    const int* __restrict__ offs, int* __restrict__ cur,
    int* __restrict__ perm, unsigned short* __restrict__ xperm) {
  int wave = threadIdx.x >> 6;
  int lane = threadIdx.x & 63;
  int t = blockIdx.x * 4 + wave;
  int pos = 0;
  if (lane == 0) {
    int e = eidx[t];
    pos = offs[e] + atomicAdd(&cur[e], 1);
    perm[pos] = t;
  }
  pos = __shfl(pos, 0);
  const float4* xr = (const float4*)(x + (size_t)t * DM);
#pragma unroll
  for (int p = 0; p < 4; ++p) {
    int col = p * 256 + lane * 4;
    float4 v = xr[p * 64 + lane];
    uint2 pk;
    pk.x = (unsigned)f2bf(v.x) | ((unsigned)f2bf(v.y) << 16);
    pk.y = (unsigned)f2bf(v.z) | ((unsigned)f2bf(v.w) << 16);
    *(uint2*)(xperm + (size_t)pos * DM + col) = pk;
  }
}

// ---- up GEMM: h = relu(x_perm @ up_W[e] + up_b[e]) -> bf16 h_perm ----
__global__ __launch_bounds__(256) void up_gemm_kernel(
    const unsigned short* __restrict__ xperm,
    const float* __restrict__ upW, const float* __restrict__ upB,
    const int* __restrict__ counts, const int* __restrict__ offs,
    unsigned short* __restrict__ hperm) {
  int e = blockIdx.y >> 6;
  int mt = blockIdx.y & 63;
  int cnt = counts[e];
  if (mt * 128 >= cnt) return;
  int row0 = offs[e] + mt * 128;
  int rows_valid = cnt - mt * 128; if (rows_valid > 128) rows_valid = 128;
  int n0 = blockIdx.x * 128;
  const float* Bg = upW + (size_t)e * DM * DFF;

  __shared__ unsigned short sA[128 * 40];
  __shared__ unsigned short sB[128 * 40];

  int tid = threadIdx.x;
  int wave = tid >> 6, lane = tid & 63;
  int wm = (wave >> 1) * 64, wn = (wave & 1) * 64;

  floatx4 acc[4][4];
#pragma unroll
  for (int i = 0; i < 4; ++i)
#pragma unroll
    for (int j = 0; j < 4; ++j) acc[i][j] = (floatx4){0.f, 0.f, 0.f, 0.f};

  int ar = tid >> 2;              // A: row within 64-row pass
  int ac = (tid & 3) * 8;         // A: col (halfwords)
  int nq = (tid & 31) * 4;        // B: n group of 4
  int kq = (tid >> 5) * 4;        // B: k group of 4

  for (int k0 = 0; k0 < DM; k0 += 32) {
    __syncthreads();
    // stage A (bf16, already K-contiguous)
#pragma unroll
    for (int p = 0; p < 2; ++p) {
      int r = p * 64 + ar;
      short8 av = *(const short8*)(xperm + (size_t)(row0 + r) * DM + k0 + ac);
      *(short8*)(sA + r * 40 + ac) = av;
    }
    // stage B: fp32 -> bf16 + transpose to [n][k]
    float4 bv[4];
#pragma unroll
    for (int dk = 0; dk < 4; ++dk)
      bv[dk] = *(const float4*)(Bg + (size_t)(k0 + kq + dk) * DFF + n0 + nq);
#pragma unroll
    for (int dn = 0; dn < 4; ++dn) {
      uint2 pk;
      pk.x = (unsigned)f2bf(f4get(bv[0], dn)) | ((unsigned)f2bf(f4get(bv[1], dn)) << 16);
      pk.y = (unsigned)f2bf(f4get(bv[2], dn)) | ((unsigned)f2bf(f4get(bv[3], dn)) << 16);
      *(uint2*)(sB + (nq + dn) * 40 + kq) = pk;
    }
    __syncthreads();
    bf16x8 a[4], b[4];
#pragma unroll
    for (int i = 0; i < 4; ++i)
      a[i] = *(const bf16x8*)(sA + (wm + i * 16 + (lane & 15)) * 40 + (lane >> 4) * 8);
#pragma unroll
    for (int j = 0; j < 4; ++j)
      b[j] = *(const bf16x8*)(sB + (wn + j * 16 + (lane & 15)) * 40 + (lane >> 4) * 8);
#pragma unroll
    for (int i = 0; i < 4; ++i)
#pragma unroll
      for (int j = 0; j < 4; ++j)
        acc[i][j] = __builtin_amdgcn_mfma_f32_16x16x32_bf16(a[i], b[j], acc[i][j], 0, 0, 0);
  }

  const float* ub = upB + (size_t)e * DFF;
#pragma unroll
  for (int i = 0; i < 4; ++i) {
#pragma unroll
    for (int r = 0; r < 4; ++r) {
      int rl = wm + i * 16 + (lane >> 4) * 4 + r;
      if (rl < rows_valid) {
        size_t rowg = (size_t)(row0 + rl) * DFF;
#pragma unroll
        for (int j = 0; j < 4; ++j) {
          int col = n0 + wn + j * 16 + (lane & 15);
          float v = acc[i][j][r] + ub[col];
          v = v > 0.f ? v : 0.f;
          hperm[rowg + col] = f2bf(v);
        }
      }
    }
  }
}

// ---- down GEMM: out[token] = h_perm @ down_W[e] + down_b[e] (fp32 scatter) ----
__global__ __launch_bounds__(256) void down_gemm_kernel(
    const unsigned short* __restrict__ hperm,
    const float* __restrict__ dW, const float* __restrict__ dB,
    const int* __restrict__ counts, const int* __restrict__ offs,
    const int* __restrict__ perm, float* __restrict__ out) {
  int e = blockIdx.y >> 6;
  int mt = blockIdx.y & 63;
  int cnt = counts[e];
  if (mt * 128 >= cnt) return;
  int row0 = offs[e] + mt * 128;
  int rows_valid = cnt - mt * 128; if (rows_valid > 128) rows_valid = 128;
  int n0 = blockIdx.x * 128;
  const float* Bg = dW + (size_t)e * DFF * DM;

  __shared__ unsigned short sA[128 * 40];
  __shared__ unsigned short sB[128 * 40];

  int tid = threadIdx.x;
  int wave = tid >> 6, lane = tid & 63;
  int wm = (wave >> 1) * 64, wn = (wave & 1) * 64;

  floatx4 acc[4][4];
#pragma unroll
  for (int i = 0; i < 4; ++i)
#pragma unroll
    for (int j = 0; j < 4; ++j) acc[i][j] = (floatx4){0.f, 0.f, 0.f, 0.f};

  int ar = tid >> 2;
  int ac = (tid & 3) * 8;
  int nq = (tid & 31) * 4;
  int kq = (tid >> 5) * 4;

  for (int k0 = 0; k0 < DFF; k0 += 32) {
    __syncthreads();
#pragma unroll
    for (int p = 0; p < 2; ++p) {
      int r = p * 64 + ar;
      short8 av = *(const short8*)(hperm + (size_t)(row0 + r) * DFF + k0 + ac);
      *(short8*)(sA + r * 40 + ac) = av;
    }
    float4 bv[4];
#pragma unroll
    for (int dk = 0; dk < 4; ++dk)
      bv[dk] = *(const float4*)(Bg + (size_t)(k0 + kq + dk) * DM + n0 + nq);
#pragma unroll
    for (int dn = 0; dn < 4; ++dn) {
      uint2 pk;
      pk.x = (unsigned)f2bf(f4get(bv[0], dn)) | ((unsigned)f2bf(f4get(bv[1], dn)) << 16);
      pk.y = (unsigned)f2bf(f4get(bv[2], dn)) | ((unsigned)f2bf(f4get(bv[3], dn)) << 16);
      *(uint2*)(sB + (nq + dn) * 40 + kq) = pk;
    }
    __syncthreads();
    bf16x8 a[4], b[4];
#pragma unroll
    for (int i = 0; i < 4; ++i)
      a[i] = *(const bf16x8*)(sA + (wm + i * 16 + (lane & 15)) * 40 + (lane >> 4) * 8);
#pragma unroll
    for (int j = 0; j < 4; ++j)
      b[j] = *(const bf16x8*)(sB + (wn + j * 16 + (lane & 15)) * 40 + (lane >> 4) * 8);
#pragma unroll
    for (int i = 0; i < 4; ++i)
#pragma unroll
      for (int j = 0; j < 4; ++j)
        acc[i][j] = __builtin_amdgcn_mfma_f32_16x16x32_bf16(a[i], b[j], acc[i][j], 0, 0, 0);
  }

  const float* db = dB + (size_t)e * DM;
#pragma unroll
  for (int i = 0; i < 4; ++i) {
#pragma unroll
    for (int r = 0; r < 4; ++r) {
      int rl = wm + i * 16 + (lane >> 4) * 4 + r;
      if (rl < rows_valid) {
        int token = perm[row0 + rl];
        size_t og = (size_t)token * DM;
#pragma unroll
        for (int j = 0; j < 4; ++j) {
          int col = n0 + wn + j * 16 + (lane & 15);
          out[og + col] = acc[i][j][r] + db[col];
        }
      }
    }
  }
}

extern "C" void kernel_launch(void* const* d_in, const int* in_sizes, int n_in,
                              void* d_out, int out_size, void* d_ws, size_t ws_size,
                              hipStream_t stream) {
  const float* x   = (const float*)d_in[0];
  const float* gW  = (const float*)d_in[1];
  const float* gb  = (const float*)d_in[2];
  const float* upW = (const float*)d_in[3];
  const float* upB = (const float*)d_in[4];
  const float* dW  = (const float*)d_in[5];
  const float* dB  = (const float*)d_in[6];
  float* out      = (float*)d_out;
  float* gate_out = out + (size_t)NTOK * DM;

  char* ws = (char*)d_ws;
  int* cnt  = (int*)(ws + WS_CNT);
  int* cur  = (int*)(ws + WS_CUR);
  int* off  = (int*)(ws + WS_OFF);
  int* eidx = (int*)(ws + WS_EIDX);
  int* perm = (int*)(ws + WS_PERM);
  unsigned short* xperm = (unsigned short*)(ws + WS_XPERM);
  unsigned short* hperm = (unsigned short*)(ws + WS_HPERM);

  zero_ctrl_kernel<<<1, 64, 0, stream>>>((int*)ws);
  gate_kernel<<<NTOK / 4, 256, 0, stream>>>(x, gW, gb, gate_out, cnt, eidx);
  offsets_kernel<<<1, 64, 0, stream>>>(cnt, off);
  scatter_kernel<<<NTOK / 4, 256, 0, stream>>>(x, eidx, off, cur, perm, xperm);
  up_gemm_kernel<<<dim3(DFF / 128, NE * 64), 256, 0, stream>>>(xperm, upW, upB, cnt, off, hperm);
  down_gemm_kernel<<<dim3(DM / 128, NE * 64), 256, 0, stream>>>(hperm, dW, dB, cnt, off, perm, out);
}

// Round 2
// 668.904 us; speedup vs baseline: 1.7098x; 1.7098x over previous
//
#include <hip/hip_runtime.h>
#include <hip/hip_bf16.h>
#include <stdint.h>

#define NTOK 8192
#define DM   1024
#define DFF  4096
#define NE   8

typedef __bf16 bf16x8 __attribute__((ext_vector_type(8)));
typedef short  short8 __attribute__((ext_vector_type(8)));
typedef float  floatx4 __attribute__((ext_vector_type(4)));

// ---- workspace layout (bytes) ----
#define WS_CNT   0                           // 8 ints
#define WS_OFF   64                          // 8 ints
#define WS_EIDX  1024                        // NTOK ints
#define WS_PERM  (WS_EIDX + NTOK * 4)        // NTOK ints
#define WS_XPERM (WS_PERM + NTOK * 4)        // (NTOK+128) x DM bf16
#define WS_HPERM (WS_XPERM + (NTOK + 128) * DM * 2)  // (NTOK+128) x DFF bf16

__device__ __forceinline__ unsigned short f2bf(float f) {
  union { float f; unsigned u; } v; v.f = f;
  return (unsigned short)((v.u + 0x7FFFu + ((v.u >> 16) & 1u)) >> 16);
}

__device__ __forceinline__ float f4get(const float4& v, int i) {
  return i == 0 ? v.x : i == 1 ? v.y : i == 2 ? v.z : v.w;
}

// one wave per token: fp32 logits, argmax (first max), one-hot out, eidx. NO atomics.
__global__ __launch_bounds__(256) void gate_kernel(
    const float* __restrict__ x, const float* __restrict__ gW,
    const float* __restrict__ gb, float* __restrict__ gate_out,
    int* __restrict__ eidx) {
  int wave = threadIdx.x >> 6;
  int lane = threadIdx.x & 63;
  int t = blockIdx.x * 4 + wave;
  const float4* xr = (const float4*)(x + (size_t)t * DM + lane * 16);
  float acc[8] = {0, 0, 0, 0, 0, 0, 0, 0};
#pragma unroll
  for (int q = 0; q < 4; ++q) {
    float4 xv = xr[q];
    int kbase = lane * 16 + q * 4;
#pragma unroll
    for (int d = 0; d < 4; ++d) {
      float xs = f4get(xv, d);
      const float4* g4 = (const float4*)(gW + (size_t)(kbase + d) * NE);
      float4 g0 = g4[0], g1 = g4[1];
      acc[0] += xs * g0.x; acc[1] += xs * g0.y;
      acc[2] += xs * g0.z; acc[3] += xs * g0.w;
      acc[4] += xs * g1.x; acc[5] += xs * g1.y;
      acc[6] += xs * g1.z; acc[7] += xs * g1.w;
    }
  }
#pragma unroll
  for (int off = 32; off > 0; off >>= 1) {
#pragma unroll
    for (int e = 0; e < 8; ++e) acc[e] += __shfl_down(acc[e], off);
  }
  if (lane == 0) {
    float best = acc[0] + gb[0];
    int bi = 0;
#pragma unroll
    for (int e = 1; e < 8; ++e) {
      float v = acc[e] + gb[e];
      if (v > best) { best = v; bi = e; }
    }
#pragma unroll
    for (int e = 0; e < 8; ++e) gate_out[(size_t)t * NE + e] = (e == bi) ? 1.0f : 0.0f;
    eidx[t] = bi;
  }
}

// single block, 1024 threads: stable counting-sort ranks via packed 16-bit scan.
__global__ __launch_bounds__(1024) void rank_kernel(
    const int* __restrict__ eidx, int* __restrict__ counts,
    int* __restrict__ offs, int* __restrict__ perm) {
  __shared__ unsigned long long sa[1024], sb[1024];
  int tid = threadIdx.x;
  int e8[8];
  unsigned long long ca = 0, cb = 0;
#pragma unroll
  for (int j = 0; j < 8; ++j) {
    int e = eidx[tid * 8 + j];
    e8[j] = e;
    if (e < 4) ca += 1ull << (16 * e);
    else       cb += 1ull << (16 * (e - 4));
  }
  sa[tid] = ca; sb[tid] = cb;
  __syncthreads();
  for (int off = 1; off < 1024; off <<= 1) {
    unsigned long long ta = 0, tb = 0;
    if (tid >= off) { ta = sa[tid - off]; tb = sb[tid - off]; }
    __syncthreads();
    sa[tid] += ta; sb[tid] += tb;
    __syncthreads();
  }
  unsigned long long tot_a = sa[1023], tot_b = sb[1023];
  int cnt_e[8];
#pragma unroll
  for (int e = 0; e < 4; ++e) cnt_e[e] = (int)((tot_a >> (16 * e)) & 0xFFFF);
#pragma unroll
  for (int e = 0; e < 4; ++e) cnt_e[e + 4] = (int)((tot_b >> (16 * e)) & 0xFFFF);
  int off_e[8]; int s = 0;
#pragma unroll
  for (int e = 0; e < 8; ++e) { off_e[e] = s; s += cnt_e[e]; }
  if (tid < 8) { counts[tid] = cnt_e[tid]; offs[tid] = off_e[tid]; }
  unsigned long long ia = sa[tid] - ca, ib = sb[tid] - cb;   // exclusive starts
  int run[8];
#pragma unroll
  for (int e = 0; e < 4; ++e) run[e] = (int)((ia >> (16 * e)) & 0xFFFF);
#pragma unroll
  for (int e = 0; e < 4; ++e) run[e + 4] = (int)((ib >> (16 * e)) & 0xFFFF);
#pragma unroll
  for (int j = 0; j < 8; ++j) {
    int e = e8[j];
    int pos = off_e[e] + run[e]++;
    perm[pos] = tid * 8 + j;
  }
}

// one wave per DEST row: gather x[perm[p]] -> bf16 xperm[p]. No atomics.
__global__ __launch_bounds__(256) void scatter_data_kernel(
    const float* __restrict__ x, const int* __restrict__ perm,
    unsigned short* __restrict__ xperm) {
  int wave = threadIdx.x >> 6, lane = threadIdx.x & 63;
  int p = blockIdx.x * 4 + wave;
  int t = perm[p];
  const float4* xr = (const float4*)(x + (size_t)t * DM);
#pragma unroll
  for (int q = 0; q < 4; ++q) {
    float4 v = xr[q * 64 + lane];
    uint2 pk;
    pk.x = (unsigned)f2bf(v.x) | ((unsigned)f2bf(v.y) << 16);
    pk.y = (unsigned)f2bf(v.z) | ((unsigned)f2bf(v.w) << 16);
    *(uint2*)(xperm + (size_t)p * DM + q * 256 + lane * 4) = pk;
  }
}

// ---- up GEMM: h = relu(x_perm @ up_W[e] + up_b[e]) -> bf16 h_perm ----
__global__ __launch_bounds__(256) void up_gemm_kernel(
    const unsigned short* __restrict__ xperm,
    const float* __restrict__ upW, const float* __restrict__ upB,
    const int* __restrict__ counts, const int* __restrict__ offs,
    unsigned short* __restrict__ hperm) {
  int e = blockIdx.y >> 6;
  int mt = blockIdx.y & 63;
  int cnt = counts[e];
  if (mt * 128 >= cnt) return;
  int row0 = offs[e] + mt * 128;
  int rows_valid = cnt - mt * 128; if (rows_valid > 128) rows_valid = 128;
  int n0 = blockIdx.x * 128;
  const float* Bg = upW + (size_t)e * DM * DFF;

  __shared__ unsigned short sA[128 * 40];
  __shared__ unsigned short sB[128 * 40];

  int tid = threadIdx.x;
  int wave = tid >> 6, lane = tid & 63;
  int wm = (wave >> 1) * 64, wn = (wave & 1) * 64;

  floatx4 acc[4][4];
#pragma unroll
  for (int i = 0; i < 4; ++i)
#pragma unroll
    for (int j = 0; j < 4; ++j) acc[i][j] = (floatx4){0.f, 0.f, 0.f, 0.f};

  int ar = tid >> 2;
  int ac = (tid & 3) * 8;
  int nq = (tid & 31) * 4;
  int kq = (tid >> 5) * 4;

  for (int k0 = 0; k0 < DM; k0 += 32) {
    __syncthreads();
#pragma unroll
    for (int p = 0; p < 2; ++p) {
      int r = p * 64 + ar;
      short8 av = *(const short8*)(xperm + (size_t)(row0 + r) * DM + k0 + ac);
      *(short8*)(sA + r * 40 + ac) = av;
    }
    float4 bv[4];
#pragma unroll
    for (int dk = 0; dk < 4; ++dk)
      bv[dk] = *(const float4*)(Bg + (size_t)(k0 + kq + dk) * DFF + n0 + nq);
#pragma unroll
    for (int dn = 0; dn < 4; ++dn) {
      uint2 pk;
      pk.x = (unsigned)f2bf(f4get(bv[0], dn)) | ((unsigned)f2bf(f4get(bv[1], dn)) << 16);
      pk.y = (unsigned)f2bf(f4get(bv[2], dn)) | ((unsigned)f2bf(f4get(bv[3], dn)) << 16);
      *(uint2*)(sB + (nq + dn) * 40 + kq) = pk;
    }
    __syncthreads();
    bf16x8 a[4], b[4];
#pragma unroll
    for (int i = 0; i < 4; ++i)
      a[i] = *(const bf16x8*)(sA + (wm + i * 16 + (lane & 15)) * 40 + (lane >> 4) * 8);
#pragma unroll
    for (int j = 0; j < 4; ++j)
      b[j] = *(const bf16x8*)(sB + (wn + j * 16 + (lane & 15)) * 40 + (lane >> 4) * 8);
#pragma unroll
    for (int i = 0; i < 4; ++i)
#pragma unroll
      for (int j = 0; j < 4; ++j)
        acc[i][j] = __builtin_amdgcn_mfma_f32_16x16x32_bf16(a[i], b[j], acc[i][j], 0, 0, 0);
  }

  const float* ub = upB + (size_t)e * DFF;
#pragma unroll
  for (int i = 0; i < 4; ++i) {
#pragma unroll
    for (int r = 0; r < 4; ++r) {
      int rl = wm + i * 16 + (lane >> 4) * 4 + r;
      if (rl < rows_valid) {
        size_t rowg = (size_t)(row0 + rl) * DFF;
#pragma unroll
        for (int j = 0; j < 4; ++j) {
          int col = n0 + wn + j * 16 + (lane & 15);
          float v = acc[i][j][r] + ub[col];
          v = v > 0.f ? v : 0.f;
          hperm[rowg + col] = f2bf(v);
        }
      }
    }
  }
}

// ---- down GEMM: out[token] = h_perm @ down_W[e] + down_b[e] (fp32 scatter) ----
__global__ __launch_bounds__(256) void down_gemm_kernel(
    const unsigned short* __restrict__ hperm,
    const float* __restrict__ dW, const float* __restrict__ dB,
    const int* __restrict__ counts, const int* __restrict__ offs,
    const int* __restrict__ perm, float* __restrict__ out) {
  int e = blockIdx.y >> 6;
  int mt = blockIdx.y & 63;
  int cnt = counts[e];
  if (mt * 128 >= cnt) return;
  int row0 = offs[e] + mt * 128;
  int rows_valid = cnt - mt * 128; if (rows_valid > 128) rows_valid = 128;
  int n0 = blockIdx.x * 128;
  const float* Bg = dW + (size_t)e * DFF * DM;

  __shared__ unsigned short sA[128 * 40];
  __shared__ unsigned short sB[128 * 40];

  int tid = threadIdx.x;
  int wave = tid >> 6, lane = tid & 63;
  int wm = (wave >> 1) * 64, wn = (wave & 1) * 64;

  floatx4 acc[4][4];
#pragma unroll
  for (int i = 0; i < 4; ++i)
#pragma unroll
    for (int j = 0; j < 4; ++j) acc[i][j] = (floatx4){0.f, 0.f, 0.f, 0.f};

  int ar = tid >> 2;
  int ac = (tid & 3) * 8;
  int nq = (tid & 31) * 4;
  int kq = (tid >> 5) * 4;

  for (int k0 = 0; k0 < DFF; k0 += 32) {
    __syncthreads();
#pragma unroll
    for (int p = 0; p < 2; ++p) {
      int r = p * 64 + ar;
      short8 av = *(const short8*)(hperm + (size_t)(row0 + r) * DFF + k0 + ac);
      *(short8*)(sA + r * 40 + ac) = av;
    }
    float4 bv[4];
#pragma unroll
    for (int dk = 0; dk < 4; ++dk)
      bv[dk] = *(const float4*)(Bg + (size_t)(k0 + kq + dk) * DM + n0 + nq);
#pragma unroll
    for (int dn = 0; dn < 4; ++dn) {
      uint2 pk;
      pk.x = (unsigned)f2bf(f4get(bv[0], dn)) | ((unsigned)f2bf(f4get(bv[1], dn)) << 16);
      pk.y = (unsigned)f2bf(f4get(bv[2], dn)) | ((unsigned)f2bf(f4get(bv[3], dn)) << 16);
      *(uint2*)(sB + (nq + dn) * 40 + kq) = pk;
    }
    __syncthreads();
    bf16x8 a[4], b[4];
#pragma unroll
    for (int i = 0; i < 4; ++i)
      a[i] = *(const bf16x8*)(sA + (wm + i * 16 + (lane & 15)) * 40 + (lane >> 4) * 8);
#pragma unroll
    for (int j = 0; j < 4; ++j)
      b[j] = *(const bf16x8*)(sB + (wn + j * 16 + (lane & 15)) * 40 + (lane >> 4) * 8);
#pragma unroll
    for (int i = 0; i < 4; ++i)
#pragma unroll
      for (int j = 0; j < 4; ++j)
        acc[i][j] = __builtin_amdgcn_mfma_f32_16x16x32_bf16(a[i], b[j], acc[i][j], 0, 0, 0);
  }

  const float* db = dB + (size_t)e * DM;
#pragma unroll
  for (int i = 0; i < 4; ++i) {
#pragma unroll
    for (int r = 0; r < 4; ++r) {
      int rl = wm + i * 16 + (lane >> 4) * 4 + r;
      if (rl < rows_valid) {
        int token = perm[row0 + rl];
        size_t og = (size_t)token * DM;
#pragma unroll
        for (int j = 0; j < 4; ++j) {
          int col = n0 + wn + j * 16 + (lane & 15);
          out[og + col] = acc[i][j][r] + db[col];
        }
      }
    }
  }
}

extern "C" void kernel_launch(void* const* d_in, const int* in_sizes, int n_in,
                              void* d_out, int out_size, void* d_ws, size_t ws_size,
                              hipStream_t stream) {
  const float* x   = (const float*)d_in[0];
  const float* gW  = (const float*)d_in[1];
  const float* gb  = (const float*)d_in[2];
  const float* upW = (const float*)d_in[3];
  const float* upB = (const float*)d_in[4];
  const float* dW  = (const float*)d_in[5];
  const float* dB  = (const float*)d_in[6];
  float* out      = (float*)d_out;
  float* gate_out = out + (size_t)NTOK * DM;

  char* ws = (char*)d_ws;
  int* cnt  = (int*)(ws + WS_CNT);
  int* off  = (int*)(ws + WS_OFF);
  int* eidx = (int*)(ws + WS_EIDX);
  int* perm = (int*)(ws + WS_PERM);
  unsigned short* xperm = (unsigned short*)(ws + WS_XPERM);
  unsigned short* hperm = (unsigned short*)(ws + WS_HPERM);

  gate_kernel<<<NTOK / 4, 256, 0, stream>>>(x, gW, gb, gate_out, eidx);
  rank_kernel<<<1, 1024, 0, stream>>>(eidx, cnt, off, perm);
  scatter_data_kernel<<<NTOK / 4, 256, 0, stream>>>(x, perm, xperm);
  up_gemm_kernel<<<dim3(DFF / 128, NE * 64), 256, 0, stream>>>(xperm, upW, upB, cnt, off, hperm);
  down_gemm_kernel<<<dim3(DM / 128, NE * 64), 256, 0, stream>>>(hperm, dW, dB, cnt, off, perm, out);
}